// Round 7
// baseline (4185.195 us; speedup 1.0000x reference)
//
#include <hip/hip_runtime.h>
#include <stdint.h>
#include <stddef.h>

// ---------------- types ----------------
typedef __bf16 bf16;
typedef __bf16 bf16x8 __attribute__((ext_vector_type(8)));
typedef __bf16 bf16x4 __attribute__((ext_vector_type(4)));
typedef float  f32x4  __attribute__((ext_vector_type(4)));
typedef int    v4i    __attribute__((ext_vector_type(4)));

// ---------------- problem constants ----------------
#define NB   64      // batch
#define NS   512     // seq len
#define NE   256     // embed dim
#define NH   256     // lstm hidden
#define NL   5       // lstm layers
#define NGC  256     // gcn hidden
#define FUSION 774   // 2H + GC + 6

__device__ __forceinline__ float sigm(float x) {
    return __fdividef(1.f, 1.f + __expf(-x));
}
__device__ __forceinline__ float tanh_(float x) {
    return __fdividef(2.f, 1.f + __expf(-2.f * x)) - 1.f;
}

// ---------------- f32 -> bf16 convert (vector of 4) ----------------
__global__ void k_cvt(const float* __restrict__ src, bf16* __restrict__ dst, int n4) {
    int i = blockIdx.x * 256 + threadIdx.x;
    if (i >= n4) return;
    f32x4 v = ((const f32x4*)src)[i];
    bf16x4 o;
    o[0] = (bf16)v[0]; o[1] = (bf16)v[1]; o[2] = (bf16)v[2]; o[3] = (bf16)v[3];
    ((bf16x4*)dst)[i] = o;
}

// ---------------- embedding gather (f32 + bf16 copies) ----------------
__global__ void k_embed(const int* __restrict__ seq, const float* __restrict__ table,
                        float* __restrict__ ef, bf16* __restrict__ eb) {
    int t  = blockIdx.x * 256 + threadIdx.x;  // < 64*512*64
    int bs = t >> 6;
    int c4 = (t & 63) << 2;
    int row = seq[bs];
    f32x4 v = *(const f32x4*)(table + (size_t)row * NE + c4);
    *(f32x4*)(ef + (size_t)bs * NE + c4) = v;
    bf16x4 o;
    o[0] = (bf16)v[0]; o[1] = (bf16)v[1]; o[2] = (bf16)v[2]; o[3] = (bf16)v[3];
    *(bf16x4*)(eb + (size_t)bs * NE + c4) = o;
}

// ---------------- bf16 MFMA GEMM: C[M,N] = A[M,K] * W[N,K]^T + bias (both bf16) ----------------
// out_mode: 0 = f32 [M,N]; 3 = bf16 gate-interleaved [tt][b][d][j][g] with
//           m = b*NS+tt, col = d*1024 + g*256 + j
__global__ __launch_bounds__(256, 2)
void k_gemm(const bf16* __restrict__ A, const bf16* __restrict__ W,
            const float* __restrict__ bias, void* __restrict__ Cout,
            int M, int N, int K, int out_mode) {
    __shared__ bf16 sA[128 * 72];
    __shared__ bf16 sB[128 * 72];
    const int mblk = M >> 7;
    int bm = blockIdx.x % mblk;
    int bn = blockIdx.x / mblk;
    int m0 = bm << 7, n0 = bn << 7;
    int tid  = threadIdx.x;
    int wave = tid >> 6, lane = tid & 63;
    int wm = wave >> 1, wn = wave & 1;
    int l15 = lane & 15, quad = lane >> 4;

    f32x4 acc[4][4] = {};

    for (int k0 = 0; k0 < K; k0 += 64) {
        int r = tid >> 1, co = (tid & 1) * 32;
        {
            const bf16* src = A + (size_t)(m0 + r) * K + k0 + co;
            bf16* dst = sA + r * 72 + co;
            *(uint4*)(dst +  0) = *(const uint4*)(src +  0);
            *(uint4*)(dst +  8) = *(const uint4*)(src +  8);
            *(uint4*)(dst + 16) = *(const uint4*)(src + 16);
            *(uint4*)(dst + 24) = *(const uint4*)(src + 24);
        }
        {
            const bf16* src = W + (size_t)(n0 + r) * K + k0 + co;
            bf16* dst = sB + r * 72 + co;
            *(uint4*)(dst +  0) = *(const uint4*)(src +  0);
            *(uint4*)(dst +  8) = *(const uint4*)(src +  8);
            *(uint4*)(dst + 16) = *(const uint4*)(src + 16);
            *(uint4*)(dst + 24) = *(const uint4*)(src + 24);
        }
        __syncthreads();
#pragma unroll
        for (int kk = 0; kk < 2; kk++) {
            bf16x8 af[4], bfr[4];
#pragma unroll
            for (int mt = 0; mt < 4; mt++)
                af[mt] = *(const bf16x8*)(sA + (wm * 64 + mt * 16 + l15) * 72 + kk * 32 + quad * 8);
#pragma unroll
            for (int nt = 0; nt < 4; nt++)
                bfr[nt] = *(const bf16x8*)(sB + (wn * 64 + nt * 16 + l15) * 72 + kk * 32 + quad * 8);
#pragma unroll
            for (int mt = 0; mt < 4; mt++)
#pragma unroll
                for (int nt = 0; nt < 4; nt++)
                    acc[mt][nt] = __builtin_amdgcn_mfma_f32_16x16x32_bf16(af[mt], bfr[nt], acc[mt][nt], 0, 0, 0);
        }
        __syncthreads();
    }
#pragma unroll
    for (int mt = 0; mt < 4; mt++) {
#pragma unroll
        for (int nt = 0; nt < 4; nt++) {
            int col = n0 + wn * 64 + nt * 16 + l15;
            float bv = bias[col];
            int row0 = m0 + wm * 64 + mt * 16 + quad * 4;
#pragma unroll
            for (int r4 = 0; r4 < 4; r4++) {
                float v = acc[mt][nt][r4] + bv;
                int r = row0 + r4;
                if (out_mode == 3) {
                    int tt = r & (NS - 1), b = r >> 9;
                    int dd = col >> 10, g = (col >> 8) & 3, j = col & 255;
                    ((bf16*)Cout)[(((((size_t)tt * 64 + b) * 2 + dd) * 256 + j) << 2) + g] = (bf16)v;
                } else {
                    ((float*)Cout)[(size_t)r * N + col] = v;
                }
            }
        }
    }
}

// ---------------- Whh int8 pre-pack + per-row scales (R4 layout) ----------------
// cell (layer,d,w, nt*4+kt), w = j-slice of 32, nt = g*2+hi, kt = K-window of 64:
// frag-lane q*16+l15r holds row (g*256 + w*32 + hi*16 + l15r), bytes k = kt*64+q*16+j'.
__global__ void k_prep_i8(const float* __restrict__ Whh0, const float* __restrict__ WhhL,
                          signed char* __restrict__ Wp8, float* __restrict__ scales) {
    int gw = blockIdx.x * 4 + (threadIdx.x >> 6);   // row id < 10240
    int lane = threadIdx.x & 63;
    int row = gw & 1023;
    int d = (gw >> 10) & 1;
    int layer = gw >> 11;
    const float* src = (layer == 0)
        ? (Whh0 + ((size_t)d * 1024 + row) * 256)
        : (WhhL + (((size_t)(layer - 1) * 2 + d) * 1024 + row) * 256);
    f32x4 v = *(const f32x4*)(src + lane * 4);
    float am = fmaxf(fmaxf(fabsf(v[0]), fabsf(v[1])), fmaxf(fabsf(v[2]), fabsf(v[3])));
#pragma unroll
    for (int off = 32; off >= 1; off >>= 1) am = fmaxf(am, __shfl_xor(am, off));
    am = fmaxf(am, 1e-8f);
    float inv = 127.f / am;
    int q0 = (int)__builtin_rintf(v[0] * inv);
    int q1 = (int)__builtin_rintf(v[1] * inv);
    int q2 = (int)__builtin_rintf(v[2] * inv);
    int q3 = (int)__builtin_rintf(v[3] * inv);
    uint32_t packed = (q0 & 255) | ((q1 & 255) << 8) | ((q2 & 255) << 16) | ((q3 & 255) << 24);
    int g = row >> 8, rem = row & 255;
    int w = rem >> 5, hi = (rem >> 4) & 1, l15r = rem & 15;
    int nt = g * 2 + hi;
    int k = lane * 4;
    int kt = k >> 6, q = (k >> 4) & 3, j = k & 15;
    size_t cell = (((size_t)layer * 2 + d) * 8 + w) * 32 + nt * 4 + kt;
    *(uint32_t*)(Wp8 + cell * 1024 + (q * 16 + l15r) * 16 + j) = packed;
    if (lane == 0)
        scales[((size_t)layer * 2 + d) * 1024 + row] = am * (1.f / (127.f * 127.f));
}

// ---------------- LSTM recurrence v4: 32 blocks x 512 threads ----------------
// 2 waves/SIMD -> 256-reg combined budget. Weights (128 AGPR/wave) are raw-asm
// MFMA srcB with "a" constraint: non-rematerializable, truly resident.
// Accumulators in VGPRs ("+v") -> partial sums are plain v_add (no accvgpr_read).
// A-fragment masking via zero-region LDS reads (no cndmask VALU).
// Unroll-by-2: LDS buffer flip folds into ds offset immediates.
#define MF0(D, A, B) asm volatile("v_mfma_i32_16x16x64_i8 %0, %1, %2, %3" : "=v"(D) : "v"(A), "a"(B), "v"(Z))
#define MFA(D, A, B) asm volatile("v_mfma_i32_16x16x64_i8 %0, %1, %2, %0" : "+v"(D) : "v"(A), "a"(B))

#define LSTM_CELL(HI, AI, AF, AG, AO, GV, WR)                                        \
  {                                                                                  \
    float pi = (float)(AI[0] + AI[1] + AI[2] + AI[3]) * scv[HI][0] + (float)GV[0];   \
    float pf = (float)(AF[0] + AF[1] + AF[2] + AF[3]) * scv[HI][1] + (float)GV[1];   \
    float pg = (float)(AG[0] + AG[1] + AG[2] + AG[3]) * scv[HI][2] + (float)GV[2];   \
    float po = (float)(AO[0] + AO[1] + AO[2] + AO[3]) * scv[HI][3] + (float)GV[3];   \
    float ig = sigm(pi), fg = sigm(pf), gc = tanh_(pg), og = sigm(po);               \
    float c = fg * cst[HI] + ig * gc; cst[HI] = c;                                   \
    float hh = og * tanh_(c);                                                        \
    ioptr[HI * 16] = (bf16)hh;                                                       \
    hsb[hwr + HI * 16 + (WR)] = (signed char)(int)__builtin_rintf(hh * 127.f);       \
  }

#define LSTM_STEP(RD, WR)                                                            \
  {                                                                                  \
    bf16x4 gn0 = *(const bf16x4*)gptr;                                               \
    bf16x4 gn1 = *(const bf16x4*)(gptr + 64);                                        \
    gptr += gstep;                                                                   \
    v4i a0 = *(const v4i*)(hsb + ra[0] + (RD));                                      \
    v4i a1 = *(const v4i*)(hsb + ra[1] + (RD));                                      \
    v4i a2 = *(const v4i*)(hsb + ra[2] + (RD));                                      \
    v4i a3 = *(const v4i*)(hsb + ra[3] + (RD));                                      \
    v4i ac0, ac1, ac2, ac3, ac4, ac5, ac6, ac7;                                      \
    MF0(ac0, a0, Wr[0][0]); MF0(ac1, a0, Wr[1][0]);                                  \
    MF0(ac2, a0, Wr[2][0]); MF0(ac3, a0, Wr[3][0]);                                  \
    MF0(ac4, a0, Wr[4][0]); MF0(ac5, a0, Wr[5][0]);                                  \
    MF0(ac6, a0, Wr[6][0]); MF0(ac7, a0, Wr[7][0]);                                  \
    MFA(ac0, a1, Wr[0][1]); MFA(ac1, a1, Wr[1][1]);                                  \
    MFA(ac2, a1, Wr[2][1]); MFA(ac3, a1, Wr[3][1]);                                  \
    MFA(ac4, a1, Wr[4][1]); MFA(ac5, a1, Wr[5][1]);                                  \
    MFA(ac6, a1, Wr[6][1]); MFA(ac7, a1, Wr[7][1]);                                  \
    MFA(ac0, a2, Wr[0][2]); MFA(ac1, a2, Wr[1][2]);                                  \
    MFA(ac2, a2, Wr[2][2]); MFA(ac3, a2, Wr[3][2]);                                  \
    MFA(ac4, a2, Wr[4][2]); MFA(ac5, a2, Wr[5][2]);                                  \
    MFA(ac6, a2, Wr[6][2]); MFA(ac7, a2, Wr[7][2]);                                  \
    MFA(ac0, a3, Wr[0][3]); MFA(ac1, a3, Wr[1][3]);                                  \
    MFA(ac2, a3, Wr[2][3]); MFA(ac3, a3, Wr[3][3]);                                  \
    MFA(ac4, a3, Wr[4][3]); MFA(ac5, a3, Wr[5][3]);                                  \
    MFA(ac6, a3, Wr[6][3]); MFA(ac7, a3, Wr[7][3]);                                  \
    asm volatile("s_nop 7\ns_nop 7\ns_nop 7"                                         \
        : "+v"(ac0), "+v"(ac1), "+v"(ac2), "+v"(ac3),                                \
          "+v"(ac4), "+v"(ac5), "+v"(ac6), "+v"(ac7));                               \
    LSTM_CELL(0, ac0, ac2, ac4, ac6, gv0, WR);                                       \
    LSTM_CELL(1, ac1, ac3, ac5, ac7, gv1, WR);                                       \
    gv0 = gn0; gv1 = gn1;                                                            \
    ioptr += iostep;                                                                 \
    __syncthreads();                                                                 \
  }

__global__ __launch_bounds__(512, 2)
void k_lstm_i8(const bf16* __restrict__ G,     // [S][64][2][256][4]
               const signed char* __restrict__ Wp8,  // [2][8][32][1024] layer slice
               const float* __restrict__ sc,   // [2][1024]
               bf16* __restrict__ io_out)      // [64][S][512]
{
    __shared__ v4i hs4[193];   // bytes 0..2047 h dbuf; 2048..2063 z0; 3072..3087 z1
    signed char* hsb = (signed char*)hs4;

    const int d  = blockIdx.x & 1;
    const int bg = blockIdx.x >> 1;       // 0..15
    const int tid = threadIdx.x;
    const int w = tid >> 6, lane = tid & 63;
    const int l15 = lane & 15, quad = lane >> 4;
    const int b = bg * 4 + quad;          // batch handled by this lane
    const int j0 = w * 32 + l15;          // first hidden index (hi=0); hi=1 -> +16

    // ---- weights -> AGPRs (pinned via asm class constraint) ----
    const signed char* wb = Wp8 + (((size_t)d * 8 + w) * 32) * 1024 + lane * 16;
    v4i Wr[8][4];
#pragma unroll
    for (int nt = 0; nt < 8; nt++)
#pragma unroll
        for (int kt = 0; kt < 4; kt++)
            Wr[nt][kt] = *(const v4i*)(wb + (nt * 4 + kt) * 1024);
#pragma unroll
    for (int nt = 0; nt < 8; nt++)
#pragma unroll
        for (int kt = 0; kt < 4; kt++)
            asm volatile("" : "+a"(Wr[nt][kt]));
    asm volatile("s_nop 7\ns_nop 7");   // accvgpr_write -> mfma srcB safety

    v4i Z = (v4i){0, 0, 0, 0};
    asm volatile("" : "+v"(Z));

    // combined scales for this lane's cells: [hi][gate]
    float scv[2][4];
#pragma unroll
    for (int hi = 0; hi < 2; hi++)
#pragma unroll
        for (int g = 0; g < 4; g++)
            scv[hi][g] = sc[d * 1024 + g * 256 + j0 + hi * 16];

    // pointers (element units)
    const int tt0 = d ? (NS - 1) : 0;
    const bf16* gptr = G + (size_t)tt0 * 131072 + ((b * 2 + d) * 256 + j0) * 4;
    const ptrdiff_t gstep = d ? -131072 : 131072;
    bf16* ioptr = io_out + (size_t)b * NS * 512 + (size_t)tt0 * 512 + d * 256 + j0;
    const ptrdiff_t iostep = d ? -512 : 512;

    // LDS addresses: A-chunk read (zero region when kt != rr), h write
    const int rr = l15 & 3;
    int ra[4];
#pragma unroll
    for (int kt = 0; kt < 4; kt++)
        ra[kt] = (rr == kt) ? (l15 * 64 + quad * 16) : 2048;
    const int hwr = quad * 256 + j0;

    // zero regions (once)
    if (tid < 2) hs4[128 + tid * 64] = (v4i){0, 0, 0, 0};

    float cst[2] = {0.f, 0.f};

    // G for t=0
    bf16x4 gv0 = *(const bf16x4*)gptr;
    bf16x4 gv1 = *(const bf16x4*)(gptr + 64);
    gptr += gstep;

    // ---- peel t = 0 (no MFMA), h(0) -> buf0 ----
    {
#pragma unroll
        for (int hi = 0; hi < 2; hi++) {
            bf16x4 GV = hi ? gv1 : gv0;
            float pi = (float)GV[0], pf = (float)GV[1], pg = (float)GV[2], po = (float)GV[3];
            float ig = sigm(pi), fg = sigm(pf), gc = tanh_(pg), og = sigm(po);
            float c = fg * cst[hi] + ig * gc; cst[hi] = c;
            float hh = og * tanh_(c);
            ioptr[hi * 16] = (bf16)hh;
            hsb[hwr + hi * 16] = (signed char)(int)__builtin_rintf(hh * 127.f);
        }
        bf16x4 gn0 = *(const bf16x4*)gptr;
        bf16x4 gn1 = *(const bf16x4*)(gptr + 64);
        gptr += gstep;
        gv0 = gn0; gv1 = gn1;
        ioptr += iostep;
    }
    __syncthreads();

    // ---- t = 1..510 as 255 pairs, then t = 511 ----
    for (int pr = 0; pr < 255; pr++) {
        LSTM_STEP(0, 1024);     // odd t: read buf0, write buf1
        LSTM_STEP(1024, 0);     // even t: read buf1, write buf0
    }
    LSTM_STEP(0, 1024);         // t = 511
}

// ---------------- GCN banded adjacency matmul -> bf16 ----------------
__global__ void k_banded(const float* __restrict__ x, const float* __restrict__ mask,
                         bf16* __restrict__ outb) {
    int t  = blockIdx.x * 256 + threadIdx.x;  // < 64*512*64
    int bs = t >> 6;
    int c4 = (t & 63) << 2;
    int s = bs & (NS - 1);
    float m  = mask[bs];
    float mn = (s < NS - 1) ? mask[bs + 1] : 0.f;
    float mp = (s > 0)      ? mask[bs - 1] : 0.f;
    float rs = m * (mp + mn) + 1e-8f;
    float cn = m * mn / rs;
    float cp = m * mp / rs;
    f32x4 vn = {}, vp = {};
    if (s < NS - 1) vn = *(const f32x4*)(x + (size_t)(bs + 1) * NGC + c4);
    if (s > 0)      vp = *(const f32x4*)(x + (size_t)(bs - 1) * NGC + c4);
    bf16x4 o;
#pragma unroll
    for (int i = 0; i < 4; i++) o[i] = (bf16)(cn * vn[i] + cp * vp[i]);
    *(bf16x4*)(outb + (size_t)bs * NGC + c4) = o;
}

// ---------------- GCN residual + layernorm + relu (one wave per row) ----------------
__global__ void k_gcnpost(const float* __restrict__ gemm_out, const float* __restrict__ x,
                          const float* __restrict__ gamma, const float* __restrict__ beta,
                          float* __restrict__ outx) {
    int row  = blockIdx.x * 4 + (threadIdx.x >> 6);
    int lane = threadIdx.x & 63;
    const float* h  = gemm_out + (size_t)row * NGC;
    const float* xr = x + (size_t)row * NGC;
    f32x4 hv = *(const f32x4*)(h + lane * 4);
    f32x4 xv = *(const f32x4*)(xr + lane * 4);
    f32x4 v;
#pragma unroll
    for (int i = 0; i < 4; i++) v[i] = hv[i] + xv[i];
    float sum = v[0] + v[1] + v[2] + v[3];
#pragma unroll
    for (int off = 32; off >= 1; off >>= 1) sum += __shfl_xor(sum, off);
    float mu = sum * (1.f / NGC);
    float sq = 0.f;
    f32x4 dv;
#pragma unroll
    for (int i = 0; i < 4; i++) { dv[i] = v[i] - mu; sq += dv[i] * dv[i]; }
#pragma unroll
    for (int off = 32; off >= 1; off >>= 1) sq += __shfl_xor(sq, off);
    float inv = rsqrtf(sq * (1.f / NGC) + 1e-5f);
    f32x4 o;
#pragma unroll
    for (int i = 0; i < 4; i++) {
        int c = lane * 4 + i;
        float y = dv[i] * inv * gamma[c] + beta[c];
        o[i] = fmaxf(y, 0.f);
    }
    *(f32x4*)(outx + (size_t)row * NGC + lane * 4) = o;
}

// ---------------- masked mean pooling ----------------
__global__ void k_pool_bf16(const bf16* __restrict__ src, const float* __restrict__ mask,
                            float* __restrict__ feat) {  // F = 512
    int b = blockIdx.x, f = threadIdx.x;
    float acc = 0.f, dm = 0.f;
    for (int t = 0; t < NS; t++) {
        float m = mask[b * NS + t];
        acc += m * (float)src[((size_t)b * NS + t) * 512 + f];
        dm += m;
    }
    feat[b * 512 + f] = acc / fmaxf(dm, 1e-8f);
}
__global__ void k_pool_f32(const float* __restrict__ src, const float* __restrict__ mask,
                           float* __restrict__ feat) {  // F = 256
    int b = blockIdx.x, f = threadIdx.x;
    float acc = 0.f, dm = 0.f;
    for (int t = 0; t < NS; t++) {
        float m = mask[b * NS + t];
        acc += m * src[((size_t)b * NS + t) * NGC + f];
        dm += m;
    }
    feat[b * NGC + f] = acc / fmaxf(dm, 1e-8f);
}

// ---------------- fused head ----------------
__global__ __launch_bounds__(512)
void k_head(const float* __restrict__ lfeat, const float* __restrict__ gfeat,
            const float* __restrict__ aux,
            const float* __restrict__ fc1W, const float* __restrict__ fc1b,
            const float* __restrict__ fc2W, const float* __restrict__ fc2b,
            const float* __restrict__ h0W, const float* __restrict__ h0b,
            const float* __restrict__ h1W, const float* __restrict__ h1b,
            float* __restrict__ out) {
    __shared__ float fused[FUSION];
    __shared__ float s1[512];
    __shared__ float s2[256];
    int m = blockIdx.x, tid = threadIdx.x;
    if (tid < 512) fused[tid] = lfeat[m * 512 + tid];
    if (tid < 256) fused[512 + tid] = gfeat[m * 256 + tid];
    if (tid < 6)   fused[768 + tid] = aux[m * 6 + tid];
    __syncthreads();
    {
        float a = fc1b[tid];
        const float* w = fc1W + (size_t)tid * FUSION;
        for (int k = 0; k < FUSION; k++) a += w[k] * fused[k];
        s1[tid] = fmaxf(a, 0.f);
    }
    __syncthreads();
    if (tid < 256) {
        float a = fc2b[tid];
        const float* w = fc2W + (size_t)tid * 512;
        for (int k = 0; k < 512; k++) a += w[k] * s1[k];
        s2[tid] = fmaxf(a, 0.f);
    }
    __syncthreads();
    if (tid < 15) {
        if (tid < 10) {
            float a = h0b[tid];
            const float* w = h0W + (size_t)tid * 256;
            for (int k = 0; k < 256; k++) a += w[k] * s2[k];
            out[m * 10 + tid] = a;
        } else {
            int n = tid - 10;
            float a = h1b[n];
            const float* w = h1W + (size_t)n * 256;
            for (int k = 0; k < 256; k++) a += w[k] * s2[k];
            out[640 + m * 5 + n] = a;
        }
    }
}

// ---------------- host launcher ----------------
extern "C" void kernel_launch(void* const* d_in, const int* in_sizes, int n_in,
                              void* d_out, int out_size, void* d_ws, size_t ws_size,
                              hipStream_t stream) {
    const int*   seq   = (const int*)d_in[0];
    const float* mask  = (const float*)d_in[1];
    const float* aux   = (const float*)d_in[2];
    const float* table = (const float*)d_in[3];
    const float* Wih0  = (const float*)d_in[4];
    const float* Whh0  = (const float*)d_in[5];
    const float* b0    = (const float*)d_in[6];
    const float* WihL  = (const float*)d_in[7];
    const float* WhhL  = (const float*)d_in[8];
    const float* bL    = (const float*)d_in[9];
    const float* gcnW  = (const float*)d_in[10];
    const float* gcnb  = (const float*)d_in[11];
    const float* gcnG  = (const float*)d_in[12];
    const float* gcnBe = (const float*)d_in[13];
    const float* fc1W  = (const float*)d_in[14];
    const float* fc1b  = (const float*)d_in[15];
    const float* fc2W  = (const float*)d_in[16];
    const float* fc2b  = (const float*)d_in[17];
    const float* h0W   = (const float*)d_in[18];
    const float* h0b   = (const float*)d_in[19];
    const float* h1W   = (const float*)d_in[20];
    const float* h1b   = (const float*)d_in[21];
    float* outp = (float*)d_out;

    char* ws = (char*)d_ws;
    const size_t MROWS = (size_t)NB * NS;          // 32768
    // region 0 (0..33.55 MB): packed weights
    signed char* Wp8 = (signed char*)(ws + 0);     // 2.62 MB
    float* wsc     = (float*)(ws + 2621440);       // 40 KB
    bf16*  Wbf     = (bf16*) (ws + 2662400);       // 9.83 MB: Wih0|WihL|gcnW (bf16)
    bf16*  wb0     = Wbf;                          // [2048][256]
    bf16*  wbL     = Wbf + 524288;                 // 4 x [2048][512]
    bf16*  wgcn    = Wbf + 524288 + 4194304;       // 3 x [256][256]
    bf16*  emb_b   = (bf16*) (ws + 33554432);      // 16.78 MB
    bf16*  io0     = (bf16*) (ws + 50331648);      // 33.55 MB
    bf16*  io1     = (bf16*) (ws + 83886080);      // 33.55 MB
    char*  Greg    =          ws + 117440512;      // 134.2 MB (G; GCN scratch aliases)
    bf16*  G       = (bf16*)  Greg;
    float* lfeat   = (float*)(ws + 251658240);     // 128 KB
    float* gfeat   = (float*)(ws + 251789312);     // 64 KB
    // GCN aliases (all inside Greg, used before G is written):
    float* gcnA  = (float*)(Greg + 0);             // f32 emb / x buffers
    float* gcnB_ = (float*)(Greg + 33554432);
    float* ggemm = (float*)(Greg + 67108864);
    bf16*  gtmp  = (bf16*) (Greg + 100663296);
    (void)ws_size; (void)n_in; (void)in_sizes; (void)out_size;

    // ---- weight prep (same every call) ----
    k_cvt<<<dim3(512),  dim3(256), 0, stream>>>(Wih0, wb0, 131072);
    k_cvt<<<dim3(4096), dim3(256), 0, stream>>>(WihL, wbL, 1048576);
    k_cvt<<<dim3(192),  dim3(256), 0, stream>>>(gcnW, wgcn, 49152);
    k_prep_i8<<<dim3(2560), dim3(256), 0, stream>>>(Whh0, WhhL, Wp8, wsc);

    // embedding (f32 copy into gcnA, bf16 copy into emb_b)
    k_embed<<<dim3(8192), dim3(256), 0, stream>>>(seq, table, gcnA, emb_b);

    // ---- GCN stack ----
    const float* xcur = gcnA;
    float* xnxt[3] = {gcnB_, gcnA, gcnB_};
    for (int i = 0; i < 3; i++) {
        k_banded<<<dim3(8192), dim3(256), 0, stream>>>(xcur, mask, gtmp);
        k_gemm<<<dim3((MROWS / 128) * (NGC / 128)), dim3(256), 0, stream>>>(
            gtmp, wgcn + (size_t)i * NGC * NGC, gcnb + i * NGC, ggemm,
            (int)MROWS, NGC, NGC, 0);
        k_gcnpost<<<dim3(8192), dim3(256), 0, stream>>>(
            ggemm, xcur, gcnG + i * NGC, gcnBe + i * NGC, xnxt[i]);
        xcur = xnxt[i];
    }
    k_pool_f32<<<dim3(NB), dim3(NGC), 0, stream>>>(xcur, mask, gfeat);

    // ---- BiLSTM stack ----
    const bf16* Xin = emb_b;
    int Kin = NE;
    bf16* ios[2] = {io0, io1};
    for (int l = 0; l < NL; l++) {
        const bf16* wih = l ? (wbL + (size_t)(l - 1) * 1048576) : wb0;
        const float* bias = l ? (bL + (size_t)(l - 1) * 2048) : b0;
        k_gemm<<<dim3((MROWS / 128) * (2048 / 128)), dim3(256), 0, stream>>>(
            Xin, wih, bias, G, (int)MROWS, 2048, Kin, 3);
        bf16* lio = ios[l & 1];
        k_lstm_i8<<<dim3(32), dim3(512), 0, stream>>>(
            G, Wp8 + (size_t)l * 524288, wsc + (size_t)l * 2048, lio);
        Xin = lio;
        Kin = 512;
    }
    k_pool_bf16<<<dim3(NB), dim3(512), 0, stream>>>(ios[(NL - 1) & 1], mask, lfeat);

    // ---- fused head ----
    k_head<<<dim3(NB), dim3(512), 0, stream>>>(
        lfeat, gfeat, aux, fc1W, fc1b, fc2W, fc2b, h0W, h0b, h1W, h1b, outp);
}